// Round 3
// baseline (2205.310 us; speedup 1.0000x reference)
//
#include <hip/hip_runtime.h>
#include <hip/hip_bf16.h>

// Problem sizes (fixed by reference)
#define N_NODES 50000
#define N_EDGES 800000
#define F_IN    128
#define HID     128
#define PROJ    512
#define N_CLS   32
#define N_GRAPHS 256
#define T_EMB   768

__device__ __forceinline__ float bf2f(unsigned short u) {
    unsigned v = ((unsigned)u) << 16;
    return __uint_as_float(v);
}
__device__ __forceinline__ unsigned short f2us(float v) {
    __hip_bfloat16 b = __float2bfloat16(v);
    union { __hip_bfloat16 b; unsigned short u; } c; c.b = b; return c.u;
}

// ---- degree via atomics over dst ----
__global__ void k_deg(const int* __restrict__ ei, float* __restrict__ deg, int nE) {
    int e = blockIdx.x * 256 + threadIdx.x;
    if (e < nE) atomicAdd(deg + ei[nE + e], 1.0f);
}

__global__ void k_dnorm(const float* __restrict__ deg, float* __restrict__ dnorm,
                        float* __restrict__ dn2, int n) {
    int i = blockIdx.x * 256 + threadIdx.x;
    if (i < n) {
        float d = deg[i] + 1.0f;
        dnorm[i] = rsqrtf(d);
        dn2[i] = 1.0f / d;
    }
}

// ---- GCN matmul: xw = h @ W (fp32), xwh = bf16(xw), outb = xw * dn2 (self-loop) ----
__global__ __launch_bounds__(256) void k_gcn_mm(const float* __restrict__ h,
    const float* __restrict__ Wf, const float* __restrict__ dn2,
    unsigned short* __restrict__ xwh, float* __restrict__ outb, int n)
{
    __shared__ float As[64][68];
    __shared__ float Ws[64][128];
    int t = threadIdx.x;
    int row0 = blockIdx.x * 64;
    int tr = t >> 4;
    int tc = t & 15;
    int r0 = tr * 4;
    int c0 = tc * 8;
    float acc[4][8];
#pragma unroll
    for (int i = 0; i < 4; i++)
#pragma unroll
        for (int j = 0; j < 8; j++) acc[i][j] = 0.f;

    for (int kc = 0; kc < 128; kc += 64) {
#pragma unroll
        for (int i = 0; i < 4; i++) {
            int l = t + i * 256;
            int r = l >> 4;
            int k4 = (l & 15) * 4;
            int gr = row0 + r;
            float4 v = make_float4(0.f, 0.f, 0.f, 0.f);
            if (gr < n) v = *(const float4*)(h + (size_t)gr * 128 + kc + k4);
            As[r][k4 + 0] = v.x; As[r][k4 + 1] = v.y;
            As[r][k4 + 2] = v.z; As[r][k4 + 3] = v.w;
        }
#pragma unroll
        for (int i = 0; i < 8; i++) {
            int l = t + i * 256;
            int kr = l >> 5;
            int c4 = (l & 31) * 4;
            float4 v = *(const float4*)(Wf + (size_t)(kc + kr) * 128 + c4);
            Ws[kr][c4 + 0] = v.x; Ws[kr][c4 + 1] = v.y;
            Ws[kr][c4 + 2] = v.z; Ws[kr][c4 + 3] = v.w;
        }
        __syncthreads();
#pragma unroll 8
        for (int k = 0; k < 64; k++) {
            float a0 = As[r0 + 0][k], a1 = As[r0 + 1][k];
            float a2 = As[r0 + 2][k], a3 = As[r0 + 3][k];
            float4 w0 = *(const float4*)&Ws[k][c0];
            float4 w1 = *(const float4*)&Ws[k][c0 + 4];
            float w[8] = { w0.x, w0.y, w0.z, w0.w, w1.x, w1.y, w1.z, w1.w };
#pragma unroll
            for (int j = 0; j < 8; j++) {
                acc[0][j] += a0 * w[j];
                acc[1][j] += a1 * w[j];
                acc[2][j] += a2 * w[j];
                acc[3][j] += a3 * w[j];
            }
        }
        __syncthreads();
    }
#pragma unroll
    for (int i = 0; i < 4; i++) {
        int gr = row0 + r0 + i;
        if (gr < n) {
            float d2 = dn2[gr];
            ushort4 u0, u1;
            u0.x = f2us(acc[i][0]); u0.y = f2us(acc[i][1]);
            u0.z = f2us(acc[i][2]); u0.w = f2us(acc[i][3]);
            u1.x = f2us(acc[i][4]); u1.y = f2us(acc[i][5]);
            u1.z = f2us(acc[i][6]); u1.w = f2us(acc[i][7]);
            *(ushort4*)(xwh + (size_t)gr * 128 + c0) = u0;
            *(ushort4*)(xwh + (size_t)gr * 128 + c0 + 4) = u1;
            float4 o0 = make_float4(acc[i][0] * d2, acc[i][1] * d2, acc[i][2] * d2, acc[i][3] * d2);
            float4 o1 = make_float4(acc[i][4] * d2, acc[i][5] * d2, acc[i][6] * d2, acc[i][7] * d2);
            *(float4*)(outb + (size_t)gr * 128 + c0) = o0;
            *(float4*)(outb + (size_t)gr * 128 + c0 + 4) = o1;
        }
    }
}

// ---- edge scatter: outb[dst] += xw[src] * dnorm[src]*dnorm[dst] ----
__global__ __launch_bounds__(256) void k_edge(const unsigned short* __restrict__ xwh,
    const int* __restrict__ ei, const float* __restrict__ dnorm,
    float* __restrict__ outb, int nE)
{
    int t = threadIdx.x;
    int e = blockIdx.x * 2 + (t >> 7);
    if (e >= nE) return;
    int f = t & 127;
    int s = ei[e];
    int d = ei[nE + e];
    float coef = dnorm[s] * dnorm[d];
    float v = bf2f(xwh[(size_t)s * 128 + f]) * coef;
    atomicAdd(outb + (size_t)d * 128 + f, v);
}

// ---- add bias, leaky_relu, in-place; accumulate BN stats ----
__global__ __launch_bounds__(256) void k_fin(float* __restrict__ outb,
    const float* __restrict__ b, float* __restrict__ stats, int n)
{
    int t = threadIdx.x;
    int f = t & 127;
    float bias = b[f];
    float s = 0.f, s2 = 0.f;
    for (int r = blockIdx.x * 2 + (t >> 7); r < n; r += gridDim.x * 2) {
        float v = outb[(size_t)r * 128 + f] + bias;
        v = v > 0.f ? v : 0.01f * v;
        outb[(size_t)r * 128 + f] = v;
        s += v; s2 += v * v;
    }
    __shared__ float sb[256], sb2[256];
    sb[t] = s; sb2[t] = s2;
    __syncthreads();
    if (t < 128) {
        atomicAdd(&stats[f], sb[t] + sb[t + 128]);
        atomicAdd(&stats[128 + f], sb2[t] + sb2[t + 128]);
    }
}

// ---- fold BN stats into scale/shift ----
__global__ void k_bnp(const float* __restrict__ stats, const float* __restrict__ g,
                      const float* __restrict__ b, float* __restrict__ scsh)
{
    int f = threadIdx.x;
    if (f < 128) {
        float inv_n = 1.0f / (float)N_NODES;
        float mu = stats[f] * inv_n;
        float var = stats[128 + f] * inv_n - mu * mu;
        float rs = rsqrtf(var + 1e-5f);
        float scale = rs * g[f];
        float shift = b[f] - mu * scale;
        scsh[f] = scale;
        scsh[128 + f] = shift;
    }
}

// ---- apply BN: h = outb*scale + shift ----
__global__ __launch_bounds__(256) void k_apply(const float* __restrict__ outb,
    const float* __restrict__ scsh, float* __restrict__ h, int n4)
{
    int i = blockIdx.x * 256 + threadIdx.x;
    if (i >= n4) return;
    int i4 = i * 4;
    int f = i4 & 127;
    float4 v = *(const float4*)(outb + i4);
    float4 sc = *(const float4*)(scsh + f);
    float4 sh = *(const float4*)(scsh + 128 + f);
    float4 o = make_float4(v.x * sc.x + sh.x, v.y * sc.y + sh.y,
                           v.z * sc.z + sh.z, v.w * sc.w + sh.w);
    *(float4*)(h + i4) = o;
}

// ---- mean pool via atomics ----
__global__ __launch_bounds__(256) void k_pool(const float* __restrict__ h,
    const int* __restrict__ batch, float* __restrict__ psum, float* __restrict__ pcnt, int n)
{
    int t = threadIdx.x;
    int r = blockIdx.x * 2 + (t >> 7);
    if (r >= n) return;
    int f = t & 127;
    int g = batch[r];
    atomicAdd(psum + (size_t)g * 128 + f, h[(size_t)r * 128 + f]);
    if (f == 0) atomicAdd(pcnt + g, 1.0f);
}

__global__ void k_gemb(const float* __restrict__ psum, const float* __restrict__ pcnt,
                       float* __restrict__ gemb, int n)
{
    int i = blockIdx.x * 256 + threadIdx.x;
    if (i < n) {
        int g = i >> 7;
        gemb[i] = psum[i] / fmaxf(pcnt[g], 1.0f);
    }
}

// ---- head layer 1: outp = in @ W1 + b1 (fp32) ----
__global__ __launch_bounds__(256) void k_head1(const float* __restrict__ in, int K,
    const float* __restrict__ W, const float* __restrict__ b, float* __restrict__ outp)
{
    __shared__ float ins[8][768];
    int t = threadIdx.x;
    int rb = blockIdx.x;
    int chunk = blockIdx.y;
    int tot = 8 * K;
    for (int l = t; l < tot; l += 256) {
        int r = l / K, k = l - r * K;
        ins[r][k] = in[(size_t)(rb * 8 + r) * K + k];
    }
    __syncthreads();
    int col = chunk * 128 + (t & 127);
    int rg = t >> 7;
    float acc[4] = { 0.f, 0.f, 0.f, 0.f };
    for (int k = 0; k < K; k++) {
        float w = W[(size_t)k * 512 + col];
#pragma unroll
        for (int i = 0; i < 4; i++) acc[i] += ins[rg * 4 + i][k] * w;
    }
    float bias = b[col];
#pragma unroll
    for (int i = 0; i < 4; i++) {
        int row = rb * 8 + rg * 4 + i;
        outp[(size_t)row * 512 + col] = acc[i] + bias;
    }
}

// ---- head layer 2 + residual + LayerNorm; fp32 proj + fp32 output ----
__global__ __launch_bounds__(256) void k_head2(const float* __restrict__ proj,
    const float* __restrict__ W2, const float* __restrict__ b2,
    const float* __restrict__ g, const float* __restrict__ be,
    float* __restrict__ projout, float* __restrict__ outf)
{
    __shared__ float prow[512], grow[512], red[256];
    int t = threadIdx.x;
    int row = blockIdx.x;
    for (int c = t; c < 512; c += 256) {
        float p = proj[(size_t)row * 512 + c];
        prow[c] = p;
        grow[c] = 0.5f * p * (1.0f + erff(p * 0.70710678118f));
    }
    __syncthreads();
    float a0 = 0.f, a1 = 0.f;
    int c0 = t, c1 = t + 256;
    for (int k = 0; k < 512; k++) {
        float gk = grow[k];
        a0 += gk * W2[(size_t)k * 512 + c0];
        a1 += gk * W2[(size_t)k * 512 + c1];
    }
    float h0 = a0 + b2[c0] + prow[c0];
    float h1 = a1 + b2[c1] + prow[c1];
    red[t] = h0 + h1;
    __syncthreads();
    for (int s = 128; s > 0; s >>= 1) { if (t < s) red[t] += red[t + s]; __syncthreads(); }
    float mu = red[0] * (1.0f / 512.0f);
    __syncthreads();
    float d0 = h0 - mu, d1 = h1 - mu;
    red[t] = d0 * d0 + d1 * d1;
    __syncthreads();
    for (int s = 128; s > 0; s >>= 1) { if (t < s) red[t] += red[t + s]; __syncthreads(); }
    float rs = rsqrtf(red[0] * (1.0f / 512.0f) + 1e-5f);
    float o0 = d0 * rs * g[c0] + be[c0];
    float o1 = d1 * rs * g[c1] + be[c1];
    projout[(size_t)row * 512 + c0] = o0;
    projout[(size_t)row * 512 + c1] = o1;
    outf[(size_t)row * 512 + c0] = o0;
    outf[(size_t)row * 512 + c1] = o1;
}

// ---- classifier + log_softmax over 32 classes ----
__global__ __launch_bounds__(256) void k_cls(const float* __restrict__ proj,
    const float* __restrict__ Wc, const float* __restrict__ bc,
    float* __restrict__ outp)
{
    __shared__ float prow[512];
    __shared__ float part[8][32];
    __shared__ float logits[32];
    __shared__ float mred, lred;
    int t = threadIdx.x;
    int row = blockIdx.x;
    for (int c = t; c < 512; c += 256) prow[c] = proj[(size_t)row * 512 + c];
    __syncthreads();
    int c = t & 31, seg = t >> 5;
    float p = 0.f;
    for (int k = seg * 64; k < seg * 64 + 64; k++)
        p += prow[k] * Wc[(size_t)k * 32 + c];
    part[seg][c] = p;
    __syncthreads();
    if (t < 32) {
        float l = bc[t];
#pragma unroll
        for (int s = 0; s < 8; s++) l += part[s][t];
        logits[t] = l;
    }
    __syncthreads();
    if (t == 0) {
        float m = logits[0];
        for (int i = 1; i < 32; i++) m = fmaxf(m, logits[i]);
        float sum = 0.f;
        for (int i = 0; i < 32; i++) sum += expf(logits[i] - m);
        mred = m; lred = logf(sum);
    }
    __syncthreads();
    if (t < 32) outp[(size_t)row * 32 + t] = logits[t] - mred - lred;
}

extern "C" void kernel_launch(void* const* d_in, const int* in_sizes, int n_in,
                              void* d_out, int out_size, void* d_ws, size_t ws_size,
                              hipStream_t stream) {
    const float* x     = (const float*)d_in[0];
    const int*   ei    = (const int*)d_in[1];
    const int*   batch = (const int*)d_in[2];
    const float* textf = (const float*)d_in[3];
    const float* gcnW  = (const float*)d_in[4];
    const float* gcnb  = (const float*)d_in[5];
    const float* bng   = (const float*)d_in[6];
    const float* bnb   = (const float*)d_in[7];
    const float* gW1   = (const float*)d_in[8];
    const float* gb1   = (const float*)d_in[9];
    const float* gW2   = (const float*)d_in[10];
    const float* gb2   = (const float*)d_in[11];
    const float* gg    = (const float*)d_in[12];
    const float* gbe   = (const float*)d_in[13];
    const float* gclW  = (const float*)d_in[14];
    const float* gclb  = (const float*)d_in[15];
    const float* tW1   = (const float*)d_in[16];
    const float* tb1   = (const float*)d_in[17];
    const float* tW2   = (const float*)d_in[18];
    const float* tb2   = (const float*)d_in[19];
    const float* tg    = (const float*)d_in[20];
    const float* tbe   = (const float*)d_in[21];
    const float* tclW  = (const float*)d_in[22];
    const float* tclb  = (const float*)d_in[23];

    const int N = N_NODES, E = N_EDGES;
    const int NF = N * HID;

    float* p = (float*)d_ws;
    float* h     = p; p += NF;
    float* outb  = p; p += NF;
    unsigned short* xwh = (unsigned short*)p; p += NF / 2;
    float* deg   = p; p += N;
    float* dnorm = p; p += N;
    float* dn2   = p; p += N;
    float* stats = p; p += 256;
    float* scsh  = p; p += 256;
    float* psum  = p; p += N_GRAPHS * HID;
    float* pcnt  = p; p += N_GRAPHS;
    float* gemb  = p; p += N_GRAPHS * HID;
    float* projg = p; p += N_GRAPHS * PROJ;
    float* gproj = p; p += N_GRAPHS * PROJ;
    float* projt = p; p += N_GRAPHS * PROJ;
    float* tproj = p; p += N_GRAPHS * PROJ;

    float* outp = (float*)d_out;
    float* o_gproj = outp;
    float* o_tproj = outp + N_GRAPHS * PROJ;
    float* o_glogp = o_tproj + N_GRAPHS * PROJ;
    float* o_tlogp = o_glogp + N_GRAPHS * N_CLS;

    // degree / norms
    hipMemsetAsync(deg, 0, (size_t)N * sizeof(float), stream);
    k_deg<<<(E + 255) / 256, 256, 0, stream>>>(ei, deg, E);
    k_dnorm<<<(N + 255) / 256, 256, 0, stream>>>(deg, dnorm, dn2, N);

    // 4 GCN layers (layer 0 reads x directly; layers 1-3 read h)
    for (int l = 0; l < 4; l++) {
        const float* hin = (l == 0) ? x : h;
        k_gcn_mm<<<(N + 63) / 64, 256, 0, stream>>>(hin, gcnW + (size_t)l * HID * HID,
                                                    dn2, xwh, outb, N);
        k_edge<<<(E + 1) / 2, 256, 0, stream>>>(xwh, ei, dnorm, outb, E);
        hipMemsetAsync(stats, 0, 256 * sizeof(float), stream);
        k_fin<<<1024, 256, 0, stream>>>(outb, gcnb + (size_t)l * HID, stats, N);
        k_bnp<<<1, 128, 0, stream>>>(stats, bng + (size_t)l * HID, bnb + (size_t)l * HID, scsh);
        k_apply<<<(NF / 4 + 255) / 256, 256, 0, stream>>>(outb, scsh, h, NF / 4);
    }

    // mean pool
    hipMemsetAsync(psum, 0, (size_t)(N_GRAPHS * HID + N_GRAPHS) * sizeof(float), stream);
    k_pool<<<(N + 1) / 2, 256, 0, stream>>>(h, batch, psum, pcnt, N);
    k_gemb<<<(N_GRAPHS * HID + 255) / 256, 256, 0, stream>>>(psum, pcnt, gemb, N_GRAPHS * HID);

    // graph head
    k_head1<<<dim3(N_GRAPHS / 8, 4), 256, 0, stream>>>(gemb, HID, gW1, gb1, projg);
    k_head2<<<N_GRAPHS, 256, 0, stream>>>(projg, gW2, gb2, gg, gbe, gproj, o_gproj);
    k_cls<<<N_GRAPHS, 256, 0, stream>>>(gproj, gclW, gclb, o_glogp);

    // text head
    k_head1<<<dim3(N_GRAPHS / 8, 4), 256, 0, stream>>>(textf, T_EMB, tW1, tb1, projt);
    k_head2<<<N_GRAPHS, 256, 0, stream>>>(projt, tW2, tb2, tg, tbe, tproj, o_tproj);
    k_cls<<<N_GRAPHS, 256, 0, stream>>>(tproj, tclW, tclb, o_tlogp);
}

// Round 4
// 1237.121 us; speedup vs baseline: 1.7826x; 1.7826x over previous
//
#include <hip/hip_runtime.h>
#include <hip/hip_bf16.h>

// Problem sizes (fixed by reference)
#define N_NODES 50000
#define N_EDGES 800000
#define F_IN    128
#define HID     128
#define PROJ    512
#define N_CLS   32
#define N_GRAPHS 256
#define T_EMB   768

__device__ __forceinline__ float bf2f(unsigned short u) {
    unsigned v = ((unsigned)u) << 16;
    return __uint_as_float(v);
}
__device__ __forceinline__ unsigned short f2us(float v) {
    __hip_bfloat16 b = __float2bfloat16(v);
    union { __hip_bfloat16 b; unsigned short u; } c; c.b = b; return c.u;
}

// ---- degree histogram (int atomics over dst) ----
__global__ void k_deg(const int* __restrict__ ei, int* __restrict__ cnt, int nE) {
    int e = blockIdx.x * 256 + threadIdx.x;
    if (e < nE) atomicAdd(cnt + ei[nE + e], 1);
}

__global__ void k_dnorm(const int* __restrict__ cnt, float* __restrict__ dnorm,
                        float* __restrict__ dn2, int n) {
    int i = blockIdx.x * 256 + threadIdx.x;
    if (i < n) {
        float d = (float)cnt[i] + 1.0f;
        dnorm[i] = rsqrtf(d);
        dn2[i] = 1.0f / d;
    }
}

// ---- exclusive scan of cnt -> rowstart (single block, 1024 threads) ----
__global__ __launch_bounds__(1024) void k_scan(const int* __restrict__ cnt,
                                               int* __restrict__ rowstart) {
    __shared__ int ps[1024];
    const int C = (N_NODES + 1023) / 1024;   // 49
    int t = threadIdx.x;
    int beg = t * C, end = min(beg + C, N_NODES);
    int sum = 0;
    for (int i = beg; i < end; i++) sum += cnt[i];
    ps[t] = sum;
    __syncthreads();
    for (int off = 1; off < 1024; off <<= 1) {
        int v = (t >= off) ? ps[t - off] : 0;
        __syncthreads();
        ps[t] += v;
        __syncthreads();
    }
    int run = (t == 0) ? 0 : ps[t - 1];
    for (int i = beg; i < end; i++) { rowstart[i] = run; run += cnt[i]; }
    if (t == 0) rowstart[N_NODES] = N_EDGES;
}

// ---- fill CSR src lists ----
__global__ void k_fill(const int* __restrict__ ei, const int* __restrict__ rowstart,
                       int* __restrict__ cursor, int* __restrict__ srcl, int nE) {
    int e = blockIdx.x * 256 + threadIdx.x;
    if (e >= nE) return;
    int s = ei[e];
    int d = ei[nE + e];
    int pos = rowstart[d] + atomicAdd(cursor + d, 1);
    srcl[pos] = s;
}

// ---- GCN matmul: xwh = bf16( (in*sc+sh) @ W ); scsh==nullptr -> identity ----
__global__ __launch_bounds__(256) void k_gcn_mm(const float* __restrict__ in,
    const float* __restrict__ Wf, const float* __restrict__ scsh,
    unsigned short* __restrict__ xwh, int n)
{
    __shared__ float As[64][68];
    __shared__ float Ws[64][128];
    int t = threadIdx.x;
    int row0 = blockIdx.x * 64;
    int tr = t >> 4;
    int tc = t & 15;
    int r0 = tr * 4;
    int c0 = tc * 8;
    float acc[4][8];
#pragma unroll
    for (int i = 0; i < 4; i++)
#pragma unroll
        for (int j = 0; j < 8; j++) acc[i][j] = 0.f;

    for (int kc = 0; kc < 128; kc += 64) {
#pragma unroll
        for (int i = 0; i < 4; i++) {
            int l = t + i * 256;
            int r = l >> 4;
            int k4 = (l & 15) * 4;
            int gr = row0 + r;
            float4 v = make_float4(0.f, 0.f, 0.f, 0.f);
            if (gr < n) v = *(const float4*)(in + (size_t)gr * 128 + kc + k4);
            if (scsh) {
                float4 sc = *(const float4*)(scsh + kc + k4);
                float4 sh = *(const float4*)(scsh + 128 + kc + k4);
                v.x = v.x * sc.x + sh.x; v.y = v.y * sc.y + sh.y;
                v.z = v.z * sc.z + sh.z; v.w = v.w * sc.w + sh.w;
            }
            As[r][k4 + 0] = v.x; As[r][k4 + 1] = v.y;
            As[r][k4 + 2] = v.z; As[r][k4 + 3] = v.w;
        }
#pragma unroll
        for (int i = 0; i < 8; i++) {
            int l = t + i * 256;
            int kr = l >> 5;
            int c4 = (l & 31) * 4;
            float4 v = *(const float4*)(Wf + (size_t)(kc + kr) * 128 + c4);
            Ws[kr][c4 + 0] = v.x; Ws[kr][c4 + 1] = v.y;
            Ws[kr][c4 + 2] = v.z; Ws[kr][c4 + 3] = v.w;
        }
        __syncthreads();
#pragma unroll 8
        for (int k = 0; k < 64; k++) {
            float a0 = As[r0 + 0][k], a1 = As[r0 + 1][k];
            float a2 = As[r0 + 2][k], a3 = As[r0 + 3][k];
            float4 w0 = *(const float4*)&Ws[k][c0];
            float4 w1 = *(const float4*)&Ws[k][c0 + 4];
            float w[8] = { w0.x, w0.y, w0.z, w0.w, w1.x, w1.y, w1.z, w1.w };
#pragma unroll
            for (int j = 0; j < 8; j++) {
                acc[0][j] += a0 * w[j];
                acc[1][j] += a1 * w[j];
                acc[2][j] += a2 * w[j];
                acc[3][j] += a3 * w[j];
            }
        }
        __syncthreads();
    }
#pragma unroll
    for (int i = 0; i < 4; i++) {
        int gr = row0 + r0 + i;
        if (gr < n) {
            ushort4 u0, u1;
            u0.x = f2us(acc[i][0]); u0.y = f2us(acc[i][1]);
            u0.z = f2us(acc[i][2]); u0.w = f2us(acc[i][3]);
            u1.x = f2us(acc[i][4]); u1.y = f2us(acc[i][5]);
            u1.z = f2us(acc[i][6]); u1.w = f2us(acc[i][7]);
            *(ushort4*)(xwh + (size_t)gr * 128 + c0) = u0;
            *(ushort4*)(xwh + (size_t)gr * 128 + c0 + 4) = u1;
        }
    }
}

// ---- fused gather + self-loop + bias + leakyReLU + BN-stat accumulation ----
// grid-stride; 2 dst rows per 256-block (128 threads per row)
__global__ __launch_bounds__(256) void k_gather(const unsigned short* __restrict__ xwh,
    const int* __restrict__ srcl, const int* __restrict__ rowstart,
    const float* __restrict__ dnorm, const float* __restrict__ dn2,
    const float* __restrict__ bias, float* __restrict__ outb,
    float* __restrict__ stats, int n)
{
    int t = threadIdx.x;
    int f = t & 127;
    int half = t >> 7;
    float bi = bias[f];
    float s = 0.f, s2 = 0.f;
    for (int r = blockIdx.x * 2 + half; r < n; r += gridDim.x * 2) {
        int e = rowstart[r], end = rowstart[r + 1];
        float acc = 0.f;
        for (; e + 1 < end; e += 2) {
            int s0 = srcl[e], s1 = srcl[e + 1];
            float v0 = bf2f(xwh[(size_t)s0 * 128 + f]) * dnorm[s0];
            float v1 = bf2f(xwh[(size_t)s1 * 128 + f]) * dnorm[s1];
            acc += v0 + v1;
        }
        if (e < end) {
            int s0 = srcl[e];
            acc += bf2f(xwh[(size_t)s0 * 128 + f]) * dnorm[s0];
        }
        float v = acc * dnorm[r] + bf2f(xwh[(size_t)r * 128 + f]) * dn2[r] + bi;
        v = v > 0.f ? v : 0.01f * v;
        outb[(size_t)r * 128 + f] = v;
        s += v; s2 += v * v;
    }
    __shared__ float sb[256], sb2[256];
    sb[t] = s; sb2[t] = s2;
    __syncthreads();
    if (t < 128) {
        atomicAdd(&stats[f], sb[t] + sb[t + 128]);
        atomicAdd(&stats[128 + f], sb2[t] + sb2[t + 128]);
    }
}

// ---- fold BN stats into scale/shift ----
__global__ void k_bnp(const float* __restrict__ stats, const float* __restrict__ g,
                      const float* __restrict__ b, float* __restrict__ scsh)
{
    int f = threadIdx.x;
    if (f < 128) {
        float inv_n = 1.0f / (float)N_NODES;
        float mu = stats[f] * inv_n;
        float var = stats[128 + f] * inv_n - mu * mu;
        float rs = rsqrtf(var + 1e-5f);
        float scale = rs * g[f];
        float shift = b[f] - mu * scale;
        scsh[f] = scale;
        scsh[128 + f] = shift;
    }
}

// ---- mean pool over outb (pre-BN); BN affine folded into k_gemb ----
__global__ __launch_bounds__(256) void k_pool(const float* __restrict__ outb,
    const int* __restrict__ batch, float* __restrict__ psum, float* __restrict__ pcnt, int n)
{
    int t = threadIdx.x;
    int r = blockIdx.x * 2 + (t >> 7);
    if (r >= n) return;
    int f = t & 127;
    int g = batch[r];
    atomicAdd(psum + (size_t)g * 128 + f, outb[(size_t)r * 128 + f]);
    if (f == 0) atomicAdd(pcnt + g, 1.0f);
}

__global__ void k_gemb(const float* __restrict__ psum, const float* __restrict__ pcnt,
                       const float* __restrict__ scsh, float* __restrict__ gemb, int n)
{
    int i = blockIdx.x * 256 + threadIdx.x;
    if (i < n) {
        int g = i >> 7;
        int f = i & 127;
        float c = pcnt[g];
        gemb[i] = (c > 0.f) ? (psum[i] / c) * scsh[f] + scsh[128 + f] : 0.f;
    }
}

// ---- head layer 1: outp = in @ W1 + b1 (fp32) ----
__global__ __launch_bounds__(256) void k_head1(const float* __restrict__ in, int K,
    const float* __restrict__ W, const float* __restrict__ b, float* __restrict__ outp)
{
    __shared__ float ins[8][768];
    int t = threadIdx.x;
    int rb = blockIdx.x;
    int chunk = blockIdx.y;
    int tot = 8 * K;
    for (int l = t; l < tot; l += 256) {
        int r = l / K, k = l - r * K;
        ins[r][k] = in[(size_t)(rb * 8 + r) * K + k];
    }
    __syncthreads();
    int col = chunk * 128 + (t & 127);
    int rg = t >> 7;
    float acc[4] = { 0.f, 0.f, 0.f, 0.f };
    for (int k = 0; k < K; k++) {
        float w = W[(size_t)k * 512 + col];
#pragma unroll
        for (int i = 0; i < 4; i++) acc[i] += ins[rg * 4 + i][k] * w;
    }
    float bias = b[col];
#pragma unroll
    for (int i = 0; i < 4; i++) {
        int row = rb * 8 + rg * 4 + i;
        outp[(size_t)row * 512 + col] = acc[i] + bias;
    }
}

// ---- head layer 2 + residual + LayerNorm; fp32 proj + fp32 output ----
__global__ __launch_bounds__(256) void k_head2(const float* __restrict__ proj,
    const float* __restrict__ W2, const float* __restrict__ b2,
    const float* __restrict__ g, const float* __restrict__ be,
    float* __restrict__ projout, float* __restrict__ outf)
{
    __shared__ float prow[512], grow[512], red[256];
    int t = threadIdx.x;
    int row = blockIdx.x;
    for (int c = t; c < 512; c += 256) {
        float p = proj[(size_t)row * 512 + c];
        prow[c] = p;
        grow[c] = 0.5f * p * (1.0f + erff(p * 0.70710678118f));
    }
    __syncthreads();
    float a0 = 0.f, a1 = 0.f;
    int c0 = t, c1 = t + 256;
    for (int k = 0; k < 512; k++) {
        float gk = grow[k];
        a0 += gk * W2[(size_t)k * 512 + c0];
        a1 += gk * W2[(size_t)k * 512 + c1];
    }
    float h0 = a0 + b2[c0] + prow[c0];
    float h1 = a1 + b2[c1] + prow[c1];
    red[t] = h0 + h1;
    __syncthreads();
    for (int s = 128; s > 0; s >>= 1) { if (t < s) red[t] += red[t + s]; __syncthreads(); }
    float mu = red[0] * (1.0f / 512.0f);
    __syncthreads();
    float d0 = h0 - mu, d1 = h1 - mu;
    red[t] = d0 * d0 + d1 * d1;
    __syncthreads();
    for (int s = 128; s > 0; s >>= 1) { if (t < s) red[t] += red[t + s]; __syncthreads(); }
    float rs = rsqrtf(red[0] * (1.0f / 512.0f) + 1e-5f);
    float o0 = d0 * rs * g[c0] + be[c0];
    float o1 = d1 * rs * g[c1] + be[c1];
    projout[(size_t)row * 512 + c0] = o0;
    projout[(size_t)row * 512 + c1] = o1;
    outf[(size_t)row * 512 + c0] = o0;
    outf[(size_t)row * 512 + c1] = o1;
}

// ---- classifier + log_softmax over 32 classes ----
__global__ __launch_bounds__(256) void k_cls(const float* __restrict__ proj,
    const float* __restrict__ Wc, const float* __restrict__ bc,
    float* __restrict__ outp)
{
    __shared__ float prow[512];
    __shared__ float part[8][32];
    __shared__ float logits[32];
    __shared__ float mred, lred;
    int t = threadIdx.x;
    int row = blockIdx.x;
    for (int c = t; c < 512; c += 256) prow[c] = proj[(size_t)row * 512 + c];
    __syncthreads();
    int c = t & 31, seg = t >> 5;
    float p = 0.f;
    for (int k = seg * 64; k < seg * 64 + 64; k++)
        p += prow[k] * Wc[(size_t)k * 32 + c];
    part[seg][c] = p;
    __syncthreads();
    if (t < 32) {
        float l = bc[t];
#pragma unroll
        for (int s = 0; s < 8; s++) l += part[s][t];
        logits[t] = l;
    }
    __syncthreads();
    if (t == 0) {
        float m = logits[0];
        for (int i = 1; i < 32; i++) m = fmaxf(m, logits[i]);
        float sum = 0.f;
        for (int i = 0; i < 32; i++) sum += expf(logits[i] - m);
        mred = m; lred = logf(sum);
    }
    __syncthreads();
    if (t < 32) outp[(size_t)row * 32 + t] = logits[t] - mred - lred;
}

extern "C" void kernel_launch(void* const* d_in, const int* in_sizes, int n_in,
                              void* d_out, int out_size, void* d_ws, size_t ws_size,
                              hipStream_t stream) {
    const float* x     = (const float*)d_in[0];
    const int*   ei    = (const int*)d_in[1];
    const int*   batch = (const int*)d_in[2];
    const float* textf = (const float*)d_in[3];
    const float* gcnW  = (const float*)d_in[4];
    const float* gcnb  = (const float*)d_in[5];
    const float* bng   = (const float*)d_in[6];
    const float* bnb   = (const float*)d_in[7];
    const float* gW1   = (const float*)d_in[8];
    const float* gb1   = (const float*)d_in[9];
    const float* gW2   = (const float*)d_in[10];
    const float* gb2   = (const float*)d_in[11];
    const float* gg    = (const float*)d_in[12];
    const float* gbe   = (const float*)d_in[13];
    const float* gclW  = (const float*)d_in[14];
    const float* gclb  = (const float*)d_in[15];
    const float* tW1   = (const float*)d_in[16];
    const float* tb1   = (const float*)d_in[17];
    const float* tW2   = (const float*)d_in[18];
    const float* tb2   = (const float*)d_in[19];
    const float* tg    = (const float*)d_in[20];
    const float* tbe   = (const float*)d_in[21];
    const float* tclW  = (const float*)d_in[22];
    const float* tclb  = (const float*)d_in[23];

    const int N = N_NODES, E = N_EDGES;
    const int NF = N * HID;

    float* p = (float*)d_ws;
    float* outb  = p; p += NF;                       // 25.6 MB
    unsigned short* xwh = (unsigned short*)p; p += NF / 2;   // 12.8 MB
    float* dnorm = p; p += N;
    float* dn2   = p; p += N;
    float* stats = p; p += 256;
    float* scsh  = p; p += 256;
    float* psum  = p; p += N_GRAPHS * HID;
    float* pcnt  = p; p += N_GRAPHS;
    float* gemb  = p; p += N_GRAPHS * HID;
    float* projg = p; p += N_GRAPHS * PROJ;
    float* gproj = p; p += N_GRAPHS * PROJ;
    float* projt = p; p += N_GRAPHS * PROJ;
    float* tproj = p; p += N_GRAPHS * PROJ;
    int* cnt      = (int*)p; p += N;
    int* rowstart = (int*)p; p += N + 1;
    int* cursor   = (int*)p; p += N;
    int* srcl     = (int*)p; p += E;                 // 3.2 MB

    float* outp = (float*)d_out;
    float* o_gproj = outp;
    float* o_tproj = outp + N_GRAPHS * PROJ;
    float* o_glogp = o_tproj + N_GRAPHS * PROJ;
    float* o_tlogp = o_glogp + N_GRAPHS * N_CLS;

    // ---- CSR build ----
    hipMemsetAsync(cnt, 0, (size_t)N * sizeof(int), stream);
    hipMemsetAsync(cursor, 0, (size_t)N * sizeof(int), stream);
    k_deg<<<(E + 255) / 256, 256, 0, stream>>>(ei, cnt, E);
    k_dnorm<<<(N + 255) / 256, 256, 0, stream>>>(cnt, dnorm, dn2, N);
    k_scan<<<1, 1024, 0, stream>>>(cnt, rowstart);
    k_fill<<<(E + 255) / 256, 256, 0, stream>>>(ei, rowstart, cursor, srcl, E);

    // ---- 4 GCN layers ----
    for (int l = 0; l < 4; l++) {
        const float* in = (l == 0) ? x : outb;
        const float* sc = (l == 0) ? nullptr : scsh;
        k_gcn_mm<<<(N + 63) / 64, 256, 0, stream>>>(in, gcnW + (size_t)l * HID * HID,
                                                    sc, xwh, N);
        hipMemsetAsync(stats, 0, 256 * sizeof(float), stream);
        k_gather<<<2048, 256, 0, stream>>>(xwh, srcl, rowstart, dnorm, dn2,
                                           gcnb + (size_t)l * HID, outb, stats, N);
        k_bnp<<<1, 128, 0, stream>>>(stats, bng + (size_t)l * HID, bnb + (size_t)l * HID, scsh);
    }

    // ---- mean pool (BN affine folded into k_gemb) ----
    hipMemsetAsync(psum, 0, (size_t)(N_GRAPHS * HID + N_GRAPHS) * sizeof(float), stream);
    k_pool<<<(N + 1) / 2, 256, 0, stream>>>(outb, batch, psum, pcnt, N);
    k_gemb<<<(N_GRAPHS * HID + 255) / 256, 256, 0, stream>>>(psum, pcnt, scsh, gemb,
                                                             N_GRAPHS * HID);

    // ---- graph head ----
    k_head1<<<dim3(N_GRAPHS / 8, 4), 256, 0, stream>>>(gemb, HID, gW1, gb1, projg);
    k_head2<<<N_GRAPHS, 256, 0, stream>>>(projg, gW2, gb2, gg, gbe, gproj, o_gproj);
    k_cls<<<N_GRAPHS, 256, 0, stream>>>(gproj, gclW, gclb, o_glogp);

    // ---- text head ----
    k_head1<<<dim3(N_GRAPHS / 8, 4), 256, 0, stream>>>(textf, T_EMB, tW1, tb1, projt);
    k_head2<<<N_GRAPHS, 256, 0, stream>>>(projt, tW2, tb2, tg, tbe, tproj, o_tproj);
    k_cls<<<N_GRAPHS, 256, 0, stream>>>(tproj, tclW, tclb, o_tlogp);
}

// Round 5
// 968.036 us; speedup vs baseline: 2.2781x; 1.2780x over previous
//
#include <hip/hip_runtime.h>
#include <hip/hip_bf16.h>

// Problem sizes (fixed by reference)
#define N_NODES 50000
#define N_EDGES 800000
#define F_IN    128
#define HID     128
#define PROJ    512
#define N_CLS   32
#define N_GRAPHS 256
#define T_EMB   768

typedef __attribute__((ext_vector_type(8))) short bf16x8;
typedef __attribute__((ext_vector_type(4))) float f32x4;

__device__ __forceinline__ float bf2f(unsigned short u) {
    unsigned v = ((unsigned)u) << 16;
    return __uint_as_float(v);
}
__device__ __forceinline__ unsigned short f2us(float v) {
    __hip_bfloat16 b = __float2bfloat16(v);
    union { __hip_bfloat16 b; unsigned short u; } c; c.b = b; return c.u;
}

// ---- degree histogram (int atomics over dst) ----
__global__ void k_deg(const int* __restrict__ ei, int* __restrict__ cnt, int nE) {
    int e = blockIdx.x * 256 + threadIdx.x;
    if (e < nE) atomicAdd(cnt + ei[nE + e], 1);
}

__global__ void k_dnorm(const int* __restrict__ cnt, float* __restrict__ dnorm,
                        float* __restrict__ dn2, int n) {
    int i = blockIdx.x * 256 + threadIdx.x;
    if (i < n) {
        float d = (float)cnt[i] + 1.0f;
        dnorm[i] = rsqrtf(d);
        dn2[i] = 1.0f / d;
    }
}

// ---- exclusive scan of cnt -> rowstart (single block, 1024 threads) ----
__global__ __launch_bounds__(1024) void k_scan(const int* __restrict__ cnt,
                                               int* __restrict__ rowstart) {
    __shared__ int ps[1024];
    const int C = (N_NODES + 1023) / 1024;   // 49
    int t = threadIdx.x;
    int beg = t * C, end = min(beg + C, N_NODES);
    int sum = 0;
    for (int i = beg; i < end; i++) sum += cnt[i];
    ps[t] = sum;
    __syncthreads();
    for (int off = 1; off < 1024; off <<= 1) {
        int v = (t >= off) ? ps[t - off] : 0;
        __syncthreads();
        ps[t] += v;
        __syncthreads();
    }
    int run = (t == 0) ? 0 : ps[t - 1];
    for (int i = beg; i < end; i++) { rowstart[i] = run; run += cnt[i]; }
    if (t == 0) rowstart[N_NODES] = N_EDGES;
}

// ---- fill CSR src lists ----
__global__ void k_fill(const int* __restrict__ ei, const int* __restrict__ rowstart,
                       int* __restrict__ cursor, int* __restrict__ srcl, int nE) {
    int e = blockIdx.x * 256 + threadIdx.x;
    if (e >= nE) return;
    int s = ei[e];
    int d = ei[nE + e];
    int pos = rowstart[d] + atomicAdd(cursor + d, 1);
    srcl[pos] = s;
}

// ---- graph boundaries from sorted batch: gstart[g] = first row with batch>=g ----
__global__ void k_gstart(const int* __restrict__ batch, int* __restrict__ gstart) {
    int r = blockIdx.x * 256 + threadIdx.x;
    if (r > N_NODES) return;
    int b  = (r < N_NODES) ? batch[r] : N_GRAPHS;
    int bp = (r > 0) ? batch[r - 1] : -1;
    for (int g = bp + 1; g <= b && g <= N_GRAPHS; g++) gstart[g] = r;
}

// ---- pre-transpose + bf16-convert all 4 GCN weights: Wt[l][n][k] = bf16(W[l][k][n]) ----
__global__ void k_wprep(const float* __restrict__ W, unsigned short* __restrict__ Wt) {
    int t = blockIdx.x * 256 + threadIdx.x;   // 4*128*128 = 65536
    if (t >= 4 * 128 * 128) return;
    int l = t >> 14;
    int k = (t >> 7) & 127;
    int n = t & 127;
    Wt[(size_t)l * 16384 + n * 128 + k] = f2us(W[(size_t)l * 16384 + k * 128 + n]);
}

// ---- GCN matmul via bf16 MFMA: xwh = bf16( (in*sc+sh) @ W ) ----
// block = 256 threads (4 waves), tile 64 rows x 128 cols, K=128
__global__ __launch_bounds__(256) void k_gcn_mm_mfma(const float* __restrict__ in,
    const unsigned short* __restrict__ Wt,   // [128 n][128 k] bf16 (n-major)
    const float* __restrict__ scsh,          // nullptr for layer 0
    unsigned short* __restrict__ xwh, int n)
{
    __shared__ __align__(16) unsigned short As[64][136];
    __shared__ __align__(16) unsigned short Bs[128][136];
    int t = threadIdx.x;
    int row0 = blockIdx.x * 64;

    // stage A: 64 rows x 128 k, fp32 -> (BN fold) -> bf16
#pragma unroll
    for (int i = 0; i < 4; i++) {
        int c = t + i * 256;            // 0..1023
        int r = c >> 4;                 // 0..63
        int k8 = (c & 15) * 8;          // 0..120
        int gr = row0 + r;
        float4 v0 = make_float4(0.f, 0.f, 0.f, 0.f);
        float4 v1 = make_float4(0.f, 0.f, 0.f, 0.f);
        if (gr < n) {
            v0 = *(const float4*)(in + (size_t)gr * 128 + k8);
            v1 = *(const float4*)(in + (size_t)gr * 128 + k8 + 4);
        }
        if (scsh) {
            float4 sc0 = *(const float4*)(scsh + k8);
            float4 sc1 = *(const float4*)(scsh + k8 + 4);
            float4 sh0 = *(const float4*)(scsh + 128 + k8);
            float4 sh1 = *(const float4*)(scsh + 128 + k8 + 4);
            v0.x = v0.x * sc0.x + sh0.x; v0.y = v0.y * sc0.y + sh0.y;
            v0.z = v0.z * sc0.z + sh0.z; v0.w = v0.w * sc0.w + sh0.w;
            v1.x = v1.x * sc1.x + sh1.x; v1.y = v1.y * sc1.y + sh1.y;
            v1.z = v1.z * sc1.z + sh1.z; v1.w = v1.w * sc1.w + sh1.w;
        }
        union { unsigned short u[8]; uint4 v; } pk;
        pk.u[0] = f2us(v0.x); pk.u[1] = f2us(v0.y); pk.u[2] = f2us(v0.z); pk.u[3] = f2us(v0.w);
        pk.u[4] = f2us(v1.x); pk.u[5] = f2us(v1.y); pk.u[6] = f2us(v1.z); pk.u[7] = f2us(v1.w);
        *(uint4*)&As[r][k8] = pk.v;
    }
    // stage B (n-major bf16 W): 128 n x 128 k
#pragma unroll
    for (int i = 0; i < 8; i++) {
        int c = t + i * 256;            // 0..2047
        int nn = c >> 4;                // 0..127
        int k8 = (c & 15) * 8;
        *(uint4*)&Bs[nn][k8] = *(const uint4*)(Wt + (size_t)nn * 128 + k8);
    }
    __syncthreads();

    int w = t >> 6, lane = t & 63;
    int m = lane & 15, quad = lane >> 4;
    int arow = w * 16 + m;
    f32x4 acc[8];
#pragma unroll
    for (int nt = 0; nt < 8; nt++) acc[nt] = (f32x4){0.f, 0.f, 0.f, 0.f};

#pragma unroll
    for (int ki = 0; ki < 4; ki++) {
        bf16x8 a = *(const bf16x8*)&As[arow][ki * 32 + quad * 8];
#pragma unroll
        for (int nt = 0; nt < 8; nt++) {
            bf16x8 b = *(const bf16x8*)&Bs[nt * 16 + m][ki * 32 + quad * 8];
            acc[nt] = __builtin_amdgcn_mfma_f32_16x16x32_bf16(a, b, acc[nt], 0, 0, 0);
        }
    }

    // epilogue: C/D layout col=lane&15, row=quad*4+reg
#pragma unroll
    for (int nt = 0; nt < 8; nt++) {
#pragma unroll
        for (int reg = 0; reg < 4; reg++) {
            int gr = row0 + w * 16 + quad * 4 + reg;
            int col = nt * 16 + m;
            if (gr < n) xwh[(size_t)gr * 128 + col] = f2us(acc[nt][reg]);
        }
    }
}

// ---- fused gather + self-loop + bias + leakyReLU + BN-stat accumulation ----
__global__ __launch_bounds__(256) void k_gather(const unsigned short* __restrict__ xwh,
    const int* __restrict__ srcl, const int* __restrict__ rowstart,
    const float* __restrict__ dnorm, const float* __restrict__ dn2,
    const float* __restrict__ bias, float* __restrict__ outb,
    float* __restrict__ stats, int n)
{
    int t = threadIdx.x;
    int f = t & 127;
    int half = t >> 7;
    float bi = bias[f];
    float s = 0.f, s2 = 0.f;
    for (int r = blockIdx.x * 2 + half; r < n; r += gridDim.x * 2) {
        int e = rowstart[r], end = rowstart[r + 1];
        float acc = 0.f;
        for (; e + 1 < end; e += 2) {
            int s0 = srcl[e], s1 = srcl[e + 1];
            float v0 = bf2f(xwh[(size_t)s0 * 128 + f]) * dnorm[s0];
            float v1 = bf2f(xwh[(size_t)s1 * 128 + f]) * dnorm[s1];
            acc += v0 + v1;
        }
        if (e < end) {
            int s0 = srcl[e];
            acc += bf2f(xwh[(size_t)s0 * 128 + f]) * dnorm[s0];
        }
        float v = acc * dnorm[r] + bf2f(xwh[(size_t)r * 128 + f]) * dn2[r] + bi;
        v = v > 0.f ? v : 0.01f * v;
        outb[(size_t)r * 128 + f] = v;
        s += v; s2 += v * v;
    }
    __shared__ float sb[256], sb2[256];
    sb[t] = s; sb2[t] = s2;
    __syncthreads();
    if (t < 128) {
        atomicAdd(&stats[f], sb[t] + sb[t + 128]);
        atomicAdd(&stats[128 + f], sb2[t] + sb2[t + 128]);
    }
}

// ---- fold BN stats into scale/shift ----
__global__ void k_bnp(const float* __restrict__ stats, const float* __restrict__ g,
                      const float* __restrict__ b, float* __restrict__ scsh)
{
    int f = threadIdx.x;
    if (f < 128) {
        float inv_n = 1.0f / (float)N_NODES;
        float mu = stats[f] * inv_n;
        float var = stats[128 + f] * inv_n - mu * mu;
        float rs = rsqrtf(var + 1e-5f);
        float scale = rs * g[f];
        float shift = b[f] - mu * scale;
        scsh[f] = scale;
        scsh[128 + f] = shift;
    }
}

// ---- segmented mean pool (batch sorted): one block per graph, BN fold ----
__global__ __launch_bounds__(256) void k_pool2(const float* __restrict__ outb,
    const int* __restrict__ gstart, const float* __restrict__ scsh,
    float* __restrict__ gemb)
{
    int g = blockIdx.x;
    int t = threadIdx.x;
    int f = t & 127;
    int half = t >> 7;
    int start = gstart[g], end = gstart[g + 1];
    int cnt = end - start;
    float s0 = 0.f, s1 = 0.f, s2 = 0.f, s3 = 0.f;
    int r = start + half;
    for (; r + 6 < end; r += 8) {
        s0 += outb[(size_t)(r    ) * 128 + f];
        s1 += outb[(size_t)(r + 2) * 128 + f];
        s2 += outb[(size_t)(r + 4) * 128 + f];
        s3 += outb[(size_t)(r + 6) * 128 + f];
    }
    for (; r < end; r += 2) s0 += outb[(size_t)r * 128 + f];
    float sum = (s0 + s1) + (s2 + s3);
    __shared__ float sb[256];
    sb[t] = sum;
    __syncthreads();
    if (t < 128) {
        float tot = sb[t] + sb[t + 128];
        float v = (cnt > 0) ? (tot / (float)cnt) * scsh[f] + scsh[128 + f] : 0.f;
        gemb[(size_t)g * 128 + f] = v;
    }
}

// ---- head layer 1: outp = in @ W1 + b1 (fp32) ----
__global__ __launch_bounds__(256) void k_head1(const float* __restrict__ in, int K,
    const float* __restrict__ W, const float* __restrict__ b, float* __restrict__ outp)
{
    __shared__ float ins[8][768];
    int t = threadIdx.x;
    int rb = blockIdx.x;
    int chunk = blockIdx.y;
    int tot = 8 * K;
    for (int l = t; l < tot; l += 256) {
        int r = l / K, k = l - r * K;
        ins[r][k] = in[(size_t)(rb * 8 + r) * K + k];
    }
    __syncthreads();
    int col = chunk * 128 + (t & 127);
    int rg = t >> 7;
    float acc[4] = { 0.f, 0.f, 0.f, 0.f };
    for (int k = 0; k < K; k++) {
        float w = W[(size_t)k * 512 + col];
#pragma unroll
        for (int i = 0; i < 4; i++) acc[i] += ins[rg * 4 + i][k] * w;
    }
    float bias = b[col];
#pragma unroll
    for (int i = 0; i < 4; i++) {
        int row = rb * 8 + rg * 4 + i;
        outp[(size_t)row * 512 + col] = acc[i] + bias;
    }
}

// ---- head layer 2 + residual + LayerNorm; fp32 proj + fp32 output ----
__global__ __launch_bounds__(256) void k_head2(const float* __restrict__ proj,
    const float* __restrict__ W2, const float* __restrict__ b2,
    const float* __restrict__ g, const float* __restrict__ be,
    float* __restrict__ projout, float* __restrict__ outf)
{
    __shared__ float prow[512], grow[512], red[256];
    int t = threadIdx.x;
    int row = blockIdx.x;
    for (int c = t; c < 512; c += 256) {
        float p = proj[(size_t)row * 512 + c];
        prow[c] = p;
        grow[c] = 0.5f * p * (1.0f + erff(p * 0.70710678118f));
    }
    __syncthreads();
    float a0 = 0.f, a1 = 0.f;
    int c0 = t, c1 = t + 256;
    for (int k = 0; k < 512; k++) {
        float gk = grow[k];
        a0 += gk * W2[(size_t)k * 512 + c0];
        a1 += gk * W2[(size_t)k * 512 + c1];
    }
    float h0 = a0 + b2[c0] + prow[c0];
    float h1 = a1 + b2[c1] + prow[c1];
    red[t] = h0 + h1;
    __syncthreads();
    for (int s = 128; s > 0; s >>= 1) { if (t < s) red[t] += red[t + s]; __syncthreads(); }
    float mu = red[0] * (1.0f / 512.0f);
    __syncthreads();
    float d0 = h0 - mu, d1 = h1 - mu;
    red[t] = d0 * d0 + d1 * d1;
    __syncthreads();
    for (int s = 128; s > 0; s >>= 1) { if (t < s) red[t] += red[t + s]; __syncthreads(); }
    float rs = rsqrtf(red[0] * (1.0f / 512.0f) + 1e-5f);
    float o0 = d0 * rs * g[c0] + be[c0];
    float o1 = d1 * rs * g[c1] + be[c1];
    projout[(size_t)row * 512 + c0] = o0;
    projout[(size_t)row * 512 + c1] = o1;
    outf[(size_t)row * 512 + c0] = o0;
    outf[(size_t)row * 512 + c1] = o1;
}

// ---- classifier + log_softmax over 32 classes ----
__global__ __launch_bounds__(256) void k_cls(const float* __restrict__ proj,
    const float* __restrict__ Wc, const float* __restrict__ bc,
    float* __restrict__ outp)
{
    __shared__ float prow[512];
    __shared__ float part[8][32];
    __shared__ float logits[32];
    __shared__ float mred, lred;
    int t = threadIdx.x;
    int row = blockIdx.x;
    for (int c = t; c < 512; c += 256) prow[c] = proj[(size_t)row * 512 + c];
    __syncthreads();
    int c = t & 31, seg = t >> 5;
    float p = 0.f;
    for (int k = seg * 64; k < seg * 64 + 64; k++)
        p += prow[k] * Wc[(size_t)k * 32 + c];
    part[seg][c] = p;
    __syncthreads();
    if (t < 32) {
        float l = bc[t];
#pragma unroll
        for (int s = 0; s < 8; s++) l += part[s][t];
        logits[t] = l;
    }
    __syncthreads();
    if (t == 0) {
        float m = logits[0];
        for (int i = 1; i < 32; i++) m = fmaxf(m, logits[i]);
        float sum = 0.f;
        for (int i = 0; i < 32; i++) sum += expf(logits[i] - m);
        mred = m; lred = logf(sum);
    }
    __syncthreads();
    if (t < 32) outp[(size_t)row * 32 + t] = logits[t] - mred - lred;
}

extern "C" void kernel_launch(void* const* d_in, const int* in_sizes, int n_in,
                              void* d_out, int out_size, void* d_ws, size_t ws_size,
                              hipStream_t stream) {
    const float* x     = (const float*)d_in[0];
    const int*   ei    = (const int*)d_in[1];
    const int*   batch = (const int*)d_in[2];
    const float* textf = (const float*)d_in[3];
    const float* gcnW  = (const float*)d_in[4];
    const float* gcnb  = (const float*)d_in[5];
    const float* bng   = (const float*)d_in[6];
    const float* bnb   = (const float*)d_in[7];
    const float* gW1   = (const float*)d_in[8];
    const float* gb1   = (const float*)d_in[9];
    const float* gW2   = (const float*)d_in[10];
    const float* gb2   = (const float*)d_in[11];
    const float* gg    = (const float*)d_in[12];
    const float* gbe   = (const float*)d_in[13];
    const float* gclW  = (const float*)d_in[14];
    const float* gclb  = (const float*)d_in[15];
    const float* tW1   = (const float*)d_in[16];
    const float* tb1   = (const float*)d_in[17];
    const float* tW2   = (const float*)d_in[18];
    const float* tb2   = (const float*)d_in[19];
    const float* tg    = (const float*)d_in[20];
    const float* tbe   = (const float*)d_in[21];
    const float* tclW  = (const float*)d_in[22];
    const float* tclb  = (const float*)d_in[23];

    const int N = N_NODES, E = N_EDGES;
    const int NF = N * HID;

    float* p = (float*)d_ws;
    float* outb  = p; p += NF;                               // 25.6 MB
    unsigned short* xwh = (unsigned short*)p; p += NF / 2;   // 12.8 MB
    unsigned short* Wt  = (unsigned short*)p; p += 4 * 16384 / 2;  // bf16 n-major weights
    float* dnorm = p; p += N;
    float* dn2   = p; p += N;
    float* stats = p; p += 256;
    float* scsh  = p; p += 256;
    float* gemb  = p; p += N_GRAPHS * HID;
    float* projg = p; p += N_GRAPHS * PROJ;
    float* gproj = p; p += N_GRAPHS * PROJ;
    float* projt = p; p += N_GRAPHS * PROJ;
    float* tproj = p; p += N_GRAPHS * PROJ;
    int* cnt      = (int*)p; p += N;
    int* rowstart = (int*)p; p += N + 1;
    int* cursor   = (int*)p; p += N;
    int* gstart   = (int*)p; p += N_GRAPHS + 1;
    int* srcl     = (int*)p; p += E;                         // 3.2 MB

    float* outp = (float*)d_out;
    float* o_gproj = outp;
    float* o_tproj = outp + N_GRAPHS * PROJ;
    float* o_glogp = o_tproj + N_GRAPHS * PROJ;
    float* o_tlogp = o_glogp + N_GRAPHS * N_CLS;

    // ---- CSR build + graph boundaries + weight prep ----
    hipMemsetAsync(cnt, 0, (size_t)N * sizeof(int), stream);
    hipMemsetAsync(cursor, 0, (size_t)N * sizeof(int), stream);
    k_deg<<<(E + 255) / 256, 256, 0, stream>>>(ei, cnt, E);
    k_dnorm<<<(N + 255) / 256, 256, 0, stream>>>(cnt, dnorm, dn2, N);
    k_scan<<<1, 1024, 0, stream>>>(cnt, rowstart);
    k_fill<<<(E + 255) / 256, 256, 0, stream>>>(ei, rowstart, cursor, srcl, E);
    k_gstart<<<(N + 256) / 256, 256, 0, stream>>>(batch, gstart);
    k_wprep<<<(4 * 16384 + 255) / 256, 256, 0, stream>>>(gcnW, Wt);

    // ---- 4 GCN layers ----
    for (int l = 0; l < 4; l++) {
        const float* in = (l == 0) ? x : outb;
        const float* sc = (l == 0) ? nullptr : scsh;
        k_gcn_mm_mfma<<<(N + 63) / 64, 256, 0, stream>>>(in, Wt + (size_t)l * 16384,
                                                         sc, xwh, N);
        hipMemsetAsync(stats, 0, 256 * sizeof(float), stream);
        k_gather<<<2048, 256, 0, stream>>>(xwh, srcl, rowstart, dnorm, dn2,
                                           gcnb + (size_t)l * HID, outb, stats, N);
        k_bnp<<<1, 128, 0, stream>>>(stats, bng + (size_t)l * HID, bnb + (size_t)l * HID, scsh);
    }

    // ---- segmented mean pool (BN affine folded) ----
    k_pool2<<<N_GRAPHS, 256, 0, stream>>>(outb, gstart, scsh, gemb);

    // ---- graph head ----
    k_head1<<<dim3(N_GRAPHS / 8, 4), 256, 0, stream>>>(gemb, HID, gW1, gb1, projg);
    k_head2<<<N_GRAPHS, 256, 0, stream>>>(projg, gW2, gb2, gg, gbe, gproj, o_gproj);
    k_cls<<<N_GRAPHS, 256, 0, stream>>>(gproj, gclW, gclb, o_glogp);

    // ---- text head ----
    k_head1<<<dim3(N_GRAPHS / 8, 4), 256, 0, stream>>>(textf, T_EMB, tW1, tb1, projt);
    k_head2<<<N_GRAPHS, 256, 0, stream>>>(projt, tW2, tb2, tg, tbe, tproj, o_tproj);
    k_cls<<<N_GRAPHS, 256, 0, stream>>>(tproj, tclW, tclb, o_tlogp);
}

// Round 6
// 831.581 us; speedup vs baseline: 2.6519x; 1.1641x over previous
//
#include <hip/hip_runtime.h>
#include <hip/hip_bf16.h>

// Problem sizes (fixed by reference)
#define N_NODES 50000
#define N_EDGES 800000
#define F_IN    128
#define HID     128
#define PROJ    512
#define N_CLS   32
#define N_GRAPHS 256
#define T_EMB   768

typedef __attribute__((ext_vector_type(8))) short bf16x8;
typedef __attribute__((ext_vector_type(4))) float f32x4;

__device__ __forceinline__ float bf2f(unsigned short u) {
    unsigned v = ((unsigned)u) << 16;
    return __uint_as_float(v);
}
__device__ __forceinline__ unsigned short f2us(float v) {
    __hip_bfloat16 b = __float2bfloat16(v);
    union { __hip_bfloat16 b; unsigned short u; } c; c.b = b; return c.u;
}

// ---- degree histogram (int atomics over dst) ----
__global__ void k_deg(const int* __restrict__ ei, int* __restrict__ cnt, int nE) {
    int e = blockIdx.x * 256 + threadIdx.x;
    if (e < nE) atomicAdd(cnt + ei[nE + e], 1);
}

__global__ void k_dnorm(const int* __restrict__ cnt, float* __restrict__ dnorm, int n) {
    int i = blockIdx.x * 256 + threadIdx.x;
    if (i < n) {
        float d = (float)cnt[i] + 1.0f;
        dnorm[i] = rsqrtf(d);
    }
}

// ---- exclusive scan of cnt -> rowstart (single block, 1024 threads) ----
__global__ __launch_bounds__(1024) void k_scan(const int* __restrict__ cnt,
                                               int* __restrict__ rowstart) {
    __shared__ int ps[1024];
    const int C = (N_NODES + 1023) / 1024;   // 49
    int t = threadIdx.x;
    int beg = t * C, end = min(beg + C, N_NODES);
    int sum = 0;
    for (int i = beg; i < end; i++) sum += cnt[i];
    ps[t] = sum;
    __syncthreads();
    for (int off = 1; off < 1024; off <<= 1) {
        int v = (t >= off) ? ps[t - off] : 0;
        __syncthreads();
        ps[t] += v;
        __syncthreads();
    }
    int run = (t == 0) ? 0 : ps[t - 1];
    for (int i = beg; i < end; i++) { rowstart[i] = run; run += cnt[i]; }
    if (t == 0) rowstart[N_NODES] = N_EDGES;
}

// ---- fill CSR src lists ----
__global__ void k_fill(const int* __restrict__ ei, const int* __restrict__ rowstart,
                       int* __restrict__ cursor, int* __restrict__ srcl, int nE) {
    int e = blockIdx.x * 256 + threadIdx.x;
    if (e >= nE) return;
    int s = ei[e];
    int d = ei[nE + e];
    int pos = rowstart[d] + atomicAdd(cursor + d, 1);
    srcl[pos] = s;
}

// ---- graph boundaries from sorted batch ----
__global__ void k_gstart(const int* __restrict__ batch, int* __restrict__ gstart) {
    int r = blockIdx.x * 256 + threadIdx.x;
    if (r > N_NODES) return;
    int b  = (r < N_NODES) ? batch[r] : N_GRAPHS;
    int bp = (r > 0) ? batch[r - 1] : -1;
    for (int g = bp + 1; g <= b && g <= N_GRAPHS; g++) gstart[g] = r;
}

// ---- pre-transpose + bf16-convert GCN weights: Wt[l][n][k] = bf16(W[l][k][n]) ----
__global__ void k_wprep(const float* __restrict__ W, unsigned short* __restrict__ Wt) {
    int t = blockIdx.x * 256 + threadIdx.x;
    if (t >= 4 * 128 * 128) return;
    int l = t >> 14;
    int k = (t >> 7) & 127;
    int n = t & 127;
    Wt[(size_t)l * 16384 + n * 128 + k] = f2us(W[(size_t)l * 16384 + k * 128 + n]);
}

// ---- GCN matmul via bf16 MFMA: ph = bf16( ((in*sc+sh) @ W) * dnorm[row] ) ----
__global__ __launch_bounds__(256) void k_gcn_mm_mfma(const float* __restrict__ in,
    const unsigned short* __restrict__ Wt,   // [128 n][128 k] bf16 (n-major)
    const float* __restrict__ scsh,          // nullptr for layer 0
    const float* __restrict__ dnorm,
    unsigned short* __restrict__ ph, int n)
{
    __shared__ __align__(16) unsigned short As[64][136];
    __shared__ __align__(16) unsigned short Bs[128][136];
    int t = threadIdx.x;
    int row0 = blockIdx.x * 64;

    // stage A: 64 rows x 128 k, fp32 -> (BN fold) -> bf16
#pragma unroll
    for (int i = 0; i < 4; i++) {
        int c = t + i * 256;
        int r = c >> 4;
        int k8 = (c & 15) * 8;
        int gr = row0 + r;
        float4 v0 = make_float4(0.f, 0.f, 0.f, 0.f);
        float4 v1 = make_float4(0.f, 0.f, 0.f, 0.f);
        if (gr < n) {
            v0 = *(const float4*)(in + (size_t)gr * 128 + k8);
            v1 = *(const float4*)(in + (size_t)gr * 128 + k8 + 4);
        }
        if (scsh) {
            float4 sc0 = *(const float4*)(scsh + k8);
            float4 sc1 = *(const float4*)(scsh + k8 + 4);
            float4 sh0 = *(const float4*)(scsh + 128 + k8);
            float4 sh1 = *(const float4*)(scsh + 128 + k8 + 4);
            v0.x = v0.x * sc0.x + sh0.x; v0.y = v0.y * sc0.y + sh0.y;
            v0.z = v0.z * sc0.z + sh0.z; v0.w = v0.w * sc0.w + sh0.w;
            v1.x = v1.x * sc1.x + sh1.x; v1.y = v1.y * sc1.y + sh1.y;
            v1.z = v1.z * sc1.z + sh1.z; v1.w = v1.w * sc1.w + sh1.w;
        }
        union { unsigned short u[8]; uint4 v; } pk;
        pk.u[0] = f2us(v0.x); pk.u[1] = f2us(v0.y); pk.u[2] = f2us(v0.z); pk.u[3] = f2us(v0.w);
        pk.u[4] = f2us(v1.x); pk.u[5] = f2us(v1.y); pk.u[6] = f2us(v1.z); pk.u[7] = f2us(v1.w);
        *(uint4*)&As[r][k8] = pk.v;
    }
    // stage B (n-major bf16 W)
#pragma unroll
    for (int i = 0; i < 8; i++) {
        int c = t + i * 256;
        int nn = c >> 4;
        int k8 = (c & 15) * 8;
        *(uint4*)&Bs[nn][k8] = *(const uint4*)(Wt + (size_t)nn * 128 + k8);
    }
    __syncthreads();

    int w = t >> 6, lane = t & 63;
    int m = lane & 15, quad = lane >> 4;
    int arow = w * 16 + m;
    f32x4 acc[8];
#pragma unroll
    for (int nt = 0; nt < 8; nt++) acc[nt] = (f32x4){0.f, 0.f, 0.f, 0.f};

#pragma unroll
    for (int ki = 0; ki < 4; ki++) {
        bf16x8 a = *(const bf16x8*)&As[arow][ki * 32 + quad * 8];
#pragma unroll
        for (int nt = 0; nt < 8; nt++) {
            bf16x8 b = *(const bf16x8*)&Bs[nt * 16 + m][ki * 32 + quad * 8];
            acc[nt] = __builtin_amdgcn_mfma_f32_16x16x32_bf16(a, b, acc[nt], 0, 0, 0);
        }
    }

    // epilogue: C/D layout col=lane&15, row=quad*4+reg; fold dnorm[row]
    float dn[4];
#pragma unroll
    for (int reg = 0; reg < 4; reg++) {
        int gr = row0 + w * 16 + quad * 4 + reg;
        dn[reg] = (gr < n) ? dnorm[gr] : 0.f;
    }
#pragma unroll
    for (int nt = 0; nt < 8; nt++) {
#pragma unroll
        for (int reg = 0; reg < 4; reg++) {
            int gr = row0 + w * 16 + quad * 4 + reg;
            int col = nt * 16 + m;
            if (gr < n) ph[(size_t)gr * 128 + col] = f2us(acc[nt][reg] * dn[reg]);
        }
    }
}

// ---- fused gather (pre-scaled p) + self-loop + bias + leakyReLU + BN stats ----
// one 64-lane wave per dst row; lane carries features {2*lane, 2*lane+1}
__global__ __launch_bounds__(256) void k_gather(const unsigned int* __restrict__ ph32,
    const int* __restrict__ srcl, const int* __restrict__ rowstart,
    const float* __restrict__ dnorm, const float* __restrict__ bias,
    float* __restrict__ outb, float* __restrict__ stats, int n)
{
    int t = threadIdx.x;
    int lane = t & 63;
    int w = t >> 6;
    int f0 = lane * 2;
    float bi0 = bias[f0], bi1 = bias[f0 + 1];
    float s0 = 0.f, s1 = 0.f, q0 = 0.f, q1 = 0.f;
    for (int r = blockIdx.x * 4 + w; r < n; r += gridDim.x * 4) {
        int e = rowstart[r], end = rowstart[r + 1];
        float x0 = 0.f, y0 = 0.f, x1 = 0.f, y1 = 0.f;
        float x2 = 0.f, y2 = 0.f, x3 = 0.f, y3 = 0.f;
        for (; e + 3 < end; e += 4) {
            int i0 = srcl[e], i1 = srcl[e + 1], i2 = srcl[e + 2], i3 = srcl[e + 3];
            unsigned u0 = ph32[(size_t)i0 * 64 + lane];
            unsigned u1 = ph32[(size_t)i1 * 64 + lane];
            unsigned u2 = ph32[(size_t)i2 * 64 + lane];
            unsigned u3 = ph32[(size_t)i3 * 64 + lane];
            x0 += bf2f((unsigned short)u0); y0 += bf2f((unsigned short)(u0 >> 16));
            x1 += bf2f((unsigned short)u1); y1 += bf2f((unsigned short)(u1 >> 16));
            x2 += bf2f((unsigned short)u2); y2 += bf2f((unsigned short)(u2 >> 16));
            x3 += bf2f((unsigned short)u3); y3 += bf2f((unsigned short)(u3 >> 16));
        }
        for (; e < end; e++) {
            unsigned u = ph32[(size_t)srcl[e] * 64 + lane];
            x0 += bf2f((unsigned short)u); y0 += bf2f((unsigned short)(u >> 16));
        }
        unsigned us = ph32[(size_t)r * 64 + lane];   // self-loop (pre-scaled)
        float sumx = (x0 + x1) + (x2 + x3) + bf2f((unsigned short)us);
        float sumy = (y0 + y1) + (y2 + y3) + bf2f((unsigned short)(us >> 16));
        float dn = dnorm[r];
        float v0 = sumx * dn + bi0;
        float v1 = sumy * dn + bi1;
        v0 = v0 > 0.f ? v0 : 0.01f * v0;
        v1 = v1 > 0.f ? v1 : 0.01f * v1;
        float2 ov = make_float2(v0, v1);
        *(float2*)(outb + (size_t)r * 128 + f0) = ov;
        s0 += v0; q0 += v0 * v0;
        s1 += v1; q1 += v1 * v1;
    }
    __shared__ float sb[4][64][2], sq[4][64][2];
    sb[w][lane][0] = s0; sb[w][lane][1] = s1;
    sq[w][lane][0] = q0; sq[w][lane][1] = q1;
    __syncthreads();
    if (t < 128) {
        int f = t, l = f >> 1, c = f & 1;
        float ss = (sb[0][l][c] + sb[1][l][c]) + (sb[2][l][c] + sb[3][l][c]);
        float qq = (sq[0][l][c] + sq[1][l][c]) + (sq[2][l][c] + sq[3][l][c]);
        atomicAdd(&stats[f], ss);
        atomicAdd(&stats[128 + f], qq);
    }
}

// ---- fold BN stats into scale/shift ----
__global__ void k_bnp(const float* __restrict__ stats, const float* __restrict__ g,
                      const float* __restrict__ b, float* __restrict__ scsh)
{
    int f = threadIdx.x;
    if (f < 128) {
        float inv_n = 1.0f / (float)N_NODES;
        float mu = stats[f] * inv_n;
        float var = stats[128 + f] * inv_n - mu * mu;
        float rs = rsqrtf(var + 1e-5f);
        float scale = rs * g[f];
        float shift = b[f] - mu * scale;
        scsh[f] = scale;
        scsh[128 + f] = shift;
    }
}

// ---- segmented mean pool (batch sorted): one block per graph, BN fold ----
__global__ __launch_bounds__(256) void k_pool2(const float* __restrict__ outb,
    const int* __restrict__ gstart, const float* __restrict__ scsh,
    float* __restrict__ gemb)
{
    int g = blockIdx.x;
    int t = threadIdx.x;
    int f = t & 127;
    int half = t >> 7;
    int start = gstart[g], end = gstart[g + 1];
    int cnt = end - start;
    float s0 = 0.f, s1 = 0.f, s2 = 0.f, s3 = 0.f;
    int r = start + half;
    for (; r + 6 < end; r += 8) {
        s0 += outb[(size_t)(r    ) * 128 + f];
        s1 += outb[(size_t)(r + 2) * 128 + f];
        s2 += outb[(size_t)(r + 4) * 128 + f];
        s3 += outb[(size_t)(r + 6) * 128 + f];
    }
    for (; r < end; r += 2) s0 += outb[(size_t)r * 128 + f];
    float sum = (s0 + s1) + (s2 + s3);
    __shared__ float sb[256];
    sb[t] = sum;
    __syncthreads();
    if (t < 128) {
        float tot = sb[t] + sb[t + 128];
        float v = (cnt > 0) ? (tot / (float)cnt) * scsh[f] + scsh[128 + f] : 0.f;
        gemb[(size_t)g * 128 + f] = v;
    }
}

// ---- head layer 1: outp = in @ W1 + b1 (fp32) ----
__global__ __launch_bounds__(256) void k_head1(const float* __restrict__ in, int K,
    const float* __restrict__ W, const float* __restrict__ b, float* __restrict__ outp)
{
    __shared__ float ins[8][768];
    int t = threadIdx.x;
    int rb = blockIdx.x;
    int chunk = blockIdx.y;
    int tot = 8 * K;
    for (int l = t; l < tot; l += 256) {
        int r = l / K, k = l - r * K;
        ins[r][k] = in[(size_t)(rb * 8 + r) * K + k];
    }
    __syncthreads();
    int col = chunk * 128 + (t & 127);
    int rg = t >> 7;
    float acc[4] = { 0.f, 0.f, 0.f, 0.f };
    for (int k = 0; k < K; k++) {
        float w = W[(size_t)k * 512 + col];
#pragma unroll
        for (int i = 0; i < 4; i++) acc[i] += ins[rg * 4 + i][k] * w;
    }
    float bias = b[col];
#pragma unroll
    for (int i = 0; i < 4; i++) {
        int row = rb * 8 + rg * 4 + i;
        outp[(size_t)row * 512 + col] = acc[i] + bias;
    }
}

// ---- head layer 2 + residual + LayerNorm; fp32 proj + fp32 output ----
__global__ __launch_bounds__(256) void k_head2(const float* __restrict__ proj,
    const float* __restrict__ W2, const float* __restrict__ b2,
    const float* __restrict__ g, const float* __restrict__ be,
    float* __restrict__ projout, float* __restrict__ outf)
{
    __shared__ float prow[512], grow[512], red[256];
    int t = threadIdx.x;
    int row = blockIdx.x;
    for (int c = t; c < 512; c += 256) {
        float p = proj[(size_t)row * 512 + c];
        prow[c] = p;
        grow[c] = 0.5f * p * (1.0f + erff(p * 0.70710678118f));
    }
    __syncthreads();
    float a0 = 0.f, a1 = 0.f;
    int c0 = t, c1 = t + 256;
    for (int k = 0; k < 512; k++) {
        float gk = grow[k];
        a0 += gk * W2[(size_t)k * 512 + c0];
        a1 += gk * W2[(size_t)k * 512 + c1];
    }
    float h0 = a0 + b2[c0] + prow[c0];
    float h1 = a1 + b2[c1] + prow[c1];
    red[t] = h0 + h1;
    __syncthreads();
    for (int s = 128; s > 0; s >>= 1) { if (t < s) red[t] += red[t + s]; __syncthreads(); }
    float mu = red[0] * (1.0f / 512.0f);
    __syncthreads();
    float d0 = h0 - mu, d1 = h1 - mu;
    red[t] = d0 * d0 + d1 * d1;
    __syncthreads();
    for (int s = 128; s > 0; s >>= 1) { if (t < s) red[t] += red[t + s]; __syncthreads(); }
    float rs = rsqrtf(red[0] * (1.0f / 512.0f) + 1e-5f);
    float o0 = d0 * rs * g[c0] + be[c0];
    float o1 = d1 * rs * g[c1] + be[c1];
    projout[(size_t)row * 512 + c0] = o0;
    projout[(size_t)row * 512 + c1] = o1;
    outf[(size_t)row * 512 + c0] = o0;
    outf[(size_t)row * 512 + c1] = o1;
}

// ---- classifier + log_softmax over 32 classes ----
__global__ __launch_bounds__(256) void k_cls(const float* __restrict__ proj,
    const float* __restrict__ Wc, const float* __restrict__ bc,
    float* __restrict__ outp)
{
    __shared__ float prow[512];
    __shared__ float part[8][32];
    __shared__ float logits[32];
    __shared__ float mred, lred;
    int t = threadIdx.x;
    int row = blockIdx.x;
    for (int c = t; c < 512; c += 256) prow[c] = proj[(size_t)row * 512 + c];
    __syncthreads();
    int c = t & 31, seg = t >> 5;
    float p = 0.f;
    for (int k = seg * 64; k < seg * 64 + 64; k++)
        p += prow[k] * Wc[(size_t)k * 32 + c];
    part[seg][c] = p;
    __syncthreads();
    if (t < 32) {
        float l = bc[t];
#pragma unroll
        for (int s = 0; s < 8; s++) l += part[s][t];
        logits[t] = l;
    }
    __syncthreads();
    if (t == 0) {
        float m = logits[0];
        for (int i = 1; i < 32; i++) m = fmaxf(m, logits[i]);
        float sum = 0.f;
        for (int i = 0; i < 32; i++) sum += expf(logits[i] - m);
        mred = m; lred = logf(sum);
    }
    __syncthreads();
    if (t < 32) outp[(size_t)row * 32 + t] = logits[t] - mred - lred;
}

extern "C" void kernel_launch(void* const* d_in, const int* in_sizes, int n_in,
                              void* d_out, int out_size, void* d_ws, size_t ws_size,
                              hipStream_t stream) {
    const float* x     = (const float*)d_in[0];
    const int*   ei    = (const int*)d_in[1];
    const int*   batch = (const int*)d_in[2];
    const float* textf = (const float*)d_in[3];
    const float* gcnW  = (const float*)d_in[4];
    const float* gcnb  = (const float*)d_in[5];
    const float* bng   = (const float*)d_in[6];
    const float* bnb   = (const float*)d_in[7];
    const float* gW1   = (const float*)d_in[8];
    const float* gb1   = (const float*)d_in[9];
    const float* gW2   = (const float*)d_in[10];
    const float* gb2   = (const float*)d_in[11];
    const float* gg    = (const float*)d_in[12];
    const float* gbe   = (const float*)d_in[13];
    const float* gclW  = (const float*)d_in[14];
    const float* gclb  = (const float*)d_in[15];
    const float* tW1   = (const float*)d_in[16];
    const float* tb1   = (const float*)d_in[17];
    const float* tW2   = (const float*)d_in[18];
    const float* tb2   = (const float*)d_in[19];
    const float* tg    = (const float*)d_in[20];
    const float* tbe   = (const float*)d_in[21];
    const float* tclW  = (const float*)d_in[22];
    const float* tclb  = (const float*)d_in[23];

    const int N = N_NODES, E = N_EDGES;
    const int NF = N * HID;

    float* p = (float*)d_ws;
    float* outb  = p; p += NF;                               // 25.6 MB
    unsigned short* ph = (unsigned short*)p; p += NF / 2;    // 12.8 MB (pre-scaled bf16)
    unsigned short* Wt = (unsigned short*)p; p += 4 * 16384 / 2;
    float* dnorm = p; p += N;
    float* stats4 = p; p += 4 * 256;
    float* scsh  = p; p += 256;
    float* gemb  = p; p += N_GRAPHS * HID;
    float* projg = p; p += N_GRAPHS * PROJ;
    float* gproj = p; p += N_GRAPHS * PROJ;
    float* projt = p; p += N_GRAPHS * PROJ;
    float* tproj = p; p += N_GRAPHS * PROJ;
    int* cnt      = (int*)p; p += N;
    int* rowstart = (int*)p; p += N + 1;
    int* cursor   = (int*)p; p += N;
    int* gstart   = (int*)p; p += N_GRAPHS + 1;
    int* srcl     = (int*)p; p += E;                         // 3.2 MB

    float* outp = (float*)d_out;
    float* o_gproj = outp;
    float* o_tproj = outp + N_GRAPHS * PROJ;
    float* o_glogp = o_tproj + N_GRAPHS * PROJ;
    float* o_tlogp = o_glogp + N_GRAPHS * N_CLS;

    // ---- CSR build + graph boundaries + weight prep ----
    hipMemsetAsync(cnt, 0, (size_t)N * sizeof(int), stream);
    hipMemsetAsync(cursor, 0, (size_t)N * sizeof(int), stream);
    hipMemsetAsync(stats4, 0, 4 * 256 * sizeof(float), stream);
    k_deg<<<(E + 255) / 256, 256, 0, stream>>>(ei, cnt, E);
    k_dnorm<<<(N + 255) / 256, 256, 0, stream>>>(cnt, dnorm, N);
    k_scan<<<1, 1024, 0, stream>>>(cnt, rowstart);
    k_fill<<<(E + 255) / 256, 256, 0, stream>>>(ei, rowstart, cursor, srcl, E);
    k_gstart<<<(N + 256) / 256, 256, 0, stream>>>(batch, gstart);
    k_wprep<<<(4 * 16384 + 255) / 256, 256, 0, stream>>>(gcnW, Wt);

    // ---- 4 GCN layers ----
    for (int l = 0; l < 4; l++) {
        const float* in = (l == 0) ? x : outb;
        const float* sc = (l == 0) ? nullptr : scsh;
        k_gcn_mm_mfma<<<(N + 63) / 64, 256, 0, stream>>>(in, Wt + (size_t)l * 16384,
                                                         sc, dnorm, ph, N);
        k_gather<<<2048, 256, 0, stream>>>((const unsigned int*)ph, srcl, rowstart,
                                           dnorm, gcnb + (size_t)l * HID, outb,
                                           stats4 + l * 256, N);
        k_bnp<<<1, 128, 0, stream>>>(stats4 + l * 256, bng + (size_t)l * HID,
                                     bnb + (size_t)l * HID, scsh);
    }

    // ---- segmented mean pool (BN affine folded) ----
    k_pool2<<<N_GRAPHS, 256, 0, stream>>>(outb, gstart, scsh, gemb);

    // ---- graph head ----
    k_head1<<<dim3(N_GRAPHS / 8, 4), 256, 0, stream>>>(gemb, HID, gW1, gb1, projg);
    k_head2<<<N_GRAPHS, 256, 0, stream>>>(projg, gW2, gb2, gg, gbe, gproj, o_gproj);
    k_cls<<<N_GRAPHS, 256, 0, stream>>>(gproj, gclW, gclb, o_glogp);

    // ---- text head ----
    k_head1<<<dim3(N_GRAPHS / 8, 4), 256, 0, stream>>>(textf, T_EMB, tW1, tb1, projt);
    k_head2<<<N_GRAPHS, 256, 0, stream>>>(projt, tW2, tb2, tg, tbe, tproj, o_tproj);
    k_cls<<<N_GRAPHS, 256, 0, stream>>>(tproj, tclW, tclb, o_tlogp);
}